// Round 8
// baseline (424.545 us; speedup 1.0000x reference)
//
#include <hip/hip_runtime.h>
#include <stdint.h>

#define Bq 32
#define Nq 512
#define Hq 128
#define NHq 8
#define HDq 16
#define Mq (Bq * Nq)   // 16384

typedef unsigned short u16;
typedef __attribute__((ext_vector_type(8))) short short8;
typedef __attribute__((ext_vector_type(4))) _Float16 half4;
typedef __attribute__((ext_vector_type(2))) __fp16 fp16x2;
typedef __attribute__((ext_vector_type(4))) float f32x4;

// ---------- dtype-flex helpers (bf: 1 = inputs are bf16, 0 = f32) ----------
__device__ __forceinline__ float bf2f(u16 v) {
    return __uint_as_float(((unsigned int)v) << 16);
}
__device__ __forceinline__ float ldin(const void* p, long idx, int bf) {
    if (bf) return bf2f(((const u16*)p)[idx]);
    return ((const float*)p)[idx];
}
__device__ __forceinline__ u16 f2bf(float v) {   // RNE
    unsigned int u = __float_as_uint(v);
    return (u16)((u + 0x7FFFu + ((u >> 16) & 1u)) >> 16);
}
__device__ __forceinline__ u16 f2h(float v) {    // f32 -> f16 bits (RNE)
    _Float16 h = (_Float16)v;
    return *(u16*)&h;
}
__device__ __forceinline__ unsigned pk2h(float a, float b) {  // packed f16 pair bits
    fp16x2 c = __builtin_amdgcn_cvt_pkrtz(a, b);
    return *(unsigned*)&c;
}
// wave-local dtype detect on first 1024 u16 of x (bf16 N(0,1) -> sane exponents)
__device__ __forceinline__ int detect_bf_wave(const void* xraw) {
    const u16* u = (const u16*)xraw;
    int lane = threadIdx.x & 63;
    int good = 0;
#pragma unroll
    for (int i = 0; i < 16; ++i) {
        u16 v = u[lane * 16 + i];
        int e = (v >> 7) & 0xFF;
        if (v == 0 || (e >= 90 && e <= 141)) good++;
    }
#pragma unroll
    for (int o = 32; o; o >>= 1) good += __shfl_xor(good, o);
    return good >= 900;
}

// ========= mega-prep: block 0 = mask/tables/kprep; 1..768 wtrans; 769.. init+LN =====
__global__ __launch_bounds__(256) void megaprep_kernel(
    const void* xraw, const void* de, const void* ab, const void* mraw,
    int* flag, float* deo, float* abo, unsigned* mbits,
    u16* kidxg, int* nkt, unsigned* tmask,
    float* h, u16* hn, const void* g1, const void* b1,
    const void* Wqr, const void* Wkr, const void* Wvr, const void* Wor,
    const void* Wf1r, const void* Wf2r,
    u16* qkvT, u16* oT, u16* f1T, u16* f2T) {
    int bid = blockIdx.x;
    int tid = threadIdx.x;
    int bf = detect_bf_wave(xraw);

    if (bid == 0) {
        __shared__ int orA, orB, orC, orD;
        __shared__ unsigned smb[512];
        if (tid == 0) { orA = 0; orB = 0; orC = 0; orD = 0; }
        __syncthreads();
        const int n = Bq * Nq;
        const uint4* p4 = (const uint4*)mraw;
        unsigned a = 0, b = 0, c = 0, d = 0;
        for (int i = tid; i < n / 16; i += 256) {
            uint4 w = p4[i];
            unsigned all = w.x | w.y | w.z | w.w;
            a |= all & 0xFEFEFEFEu;
            b |= all & 0x0000FF00u;
            c |= all & 0xFFFFFF00u;
            d |= w.y | w.w;
        }
        if (a) atomicOr(&orA, 1);
        if (b) atomicOr(&orB, 1);
        if (c) atomicOr(&orC, 1);
        if (d) atomicOr(&orD, 1);
        __syncthreads();
        if (tid == 0) *flag = bf;
        int mode;  // 0 bool8, 1 int32, 2 int64, 3 bf16, 4 f32
        if (orA) mode = orB ? 3 : 4;
        else if (orC) mode = 0;
        else mode = orD ? 1 : 2;
        for (int i = tid; i < 1200; i += 256) deo[i] = ldin(de, i, bf);
        if (tid < 24) abo[tid] = ldin(ab, tid, bf);
        const unsigned char* p = (const unsigned char*)mraw;
        for (int wI = tid; wI < 512; wI += 256) {
            unsigned word = 0;
            for (int j = 0; j < 32; ++j) {
                int i = wI * 32 + j;
                int v;
                switch (mode) {
                    case 0: v = p[i]; break;
                    case 1: v = ((const int*)p)[i]; break;
                    case 2: v = (int)((const long long*)p)[i]; break;
                    case 3: v = ((const u16*)p)[i] != 0; break;
                    default: v = (((const float*)p)[i] != 0.0f); break;
                }
                if (v) word |= 1u << j;
            }
            mbits[wI] = word;
            smb[wI] = word;
        }
        __syncthreads();
        // kprep: waves handle batches
        int wv = tid >> 6, lane = tid & 63;
        for (int bb = wv; bb < 32; bb += 4) {
            int pos_base = 0;
            for (int w = 0; w < 8; ++w) {
                unsigned lo = smb[bb * 16 + 2 * w], hi = smb[bb * 16 + 2 * w + 1];
                unsigned long long word = ((unsigned long long)hi << 32) | lo;
                unsigned long long un = ~word;   // 1 = unmasked
                int bit = (int)((un >> lane) & 1ull);
                unsigned long long before = un & ((1ull << lane) - 1ull);
                int pos = pos_base + __popcll(before);
                if (bit) kidxg[bb * 512 + pos] = (u16)(w * 64 + lane);
                pos_base += __popcll(un);
            }
            int nk = pos_base;
            int nkp = (nk + 31) & ~31;
            if (nkp == 0) nkp = 32;
            int nt = nkp >> 5;
            for (int j = nk + lane; j < nkp; j += 64) kidxg[bb * 512 + j] = 0;
            if (lane == 0) {
                nkt[bb] = nt;
                for (int t = 0; t < 16; ++t) tmask[bb * 16 + t] = 0;
                int rem = nk & 31;
                if (rem) tmask[bb * 16 + nt - 1] = 0xFFFFFFFFu << rem;
                if (nk == 0) tmask[bb * 16] = 0xFFFFFFFFu;
            }
        }
    } else if (bid <= 768) {
        // weight transpose: W[K][N] -> WT[N][K] bf16
        int bid2 = bid - 1;
        int l = bid2 >> 8, r = bid2 & 255;
        const void* src; u16* dst; long soff, doff; int Kd, Nd, t;
        if (r < 64) {
            int mat = r >> 4; t = r & 15; Kd = 128; Nd = 128;
            soff = (long)l * 16384;
            if (mat == 0)      { src = Wqr; dst = qkvT; doff = (long)l * 49152; }
            else if (mat == 1) { src = Wkr; dst = qkvT; doff = (long)l * 49152 + 16384; }
            else if (mat == 2) { src = Wvr; dst = qkvT; doff = (long)l * 49152 + 32768; }
            else               { src = Wor; dst = oT;   doff = (long)l * 16384; }
        } else if (r < 192) {
            t = r - 64; Kd = 128; Nd = 1024;
            src = Wf1r; soff = (long)l * 131072; dst = f1T; doff = (long)l * 131072;
        } else {
            t = r - 192; Kd = 512; Nd = 128;
            src = Wf2r; soff = (long)l * 65536; dst = f2T; doff = (long)l * 65536;
        }
        int ntile = Nd >> 5;
        int tk = t / ntile, tn = t % ntile;
        __shared__ u16 Ts[32][33];
        int rr = tid >> 3, cc0 = (tid & 7) * 4;
#pragma unroll
        for (int i = 0; i < 4; ++i) {
            long idx = soff + (long)(tk * 32 + rr) * Nd + tn * 32 + cc0 + i;
            Ts[rr][cc0 + i] = f2bf(ldin(src, idx, bf));
        }
        __syncthreads();
#pragma unroll
        for (int i = 0; i < 4; ++i) {
            long idx = doff + (long)(tn * 32 + rr) * Kd + tk * 32 + cc0 + i;
            dst[idx] = Ts[cc0 + i][rr];
        }
    } else {
        // init + first LN: x -> h (f32), hn = LN(x) (bf16)
        int row = (bid - 769) * 4 + (tid >> 6);
        int lane = tid & 63;
        float x0 = ldin(xraw, (long)row * Hq + lane, bf);
        float x1 = ldin(xraw, (long)row * Hq + lane + 64, bf);
        h[(size_t)row * Hq + lane] = x0;
        h[(size_t)row * Hq + lane + 64] = x1;
        float s = x0 + x1, s2 = x0 * x0 + x1 * x1;
#pragma unroll
        for (int o = 32; o; o >>= 1) {
            s += __shfl_xor(s, o);
            s2 += __shfl_xor(s2, o);
        }
        float mu = s * (1.0f / 128.0f);
        float var = fmaxf(s2 * (1.0f / 128.0f) - mu * mu, 0.0f);
        float rr = rsqrtf(var + 1e-5f);
        float g0 = ldin(g1, lane, bf), g1v = ldin(g1, lane + 64, bf);
        float b0 = ldin(b1, lane, bf), b1v = ldin(b1, lane + 64, bf);
        hn[(size_t)row * Hq + lane]      = f2bf((x0 - mu) * rr * g0 + b0);
        hn[(size_t)row * Hq + lane + 64] = f2bf((x1 - mu) * rr * g1v + b1v);
    }
}

// ---------- binsc: compressed, pre-scaled (x4) bin bytes from dist ----------
__global__ __launch_bounds__(256) void binsc_kernel(
    const void* __restrict__ dist, const u16* __restrict__ kidxg,
    const int* __restrict__ nkt, unsigned char* __restrict__ binsc,
    const int* flagp) {
    int bf = *flagp;
    int b = blockIdx.y;
    int q0 = blockIdx.x * 8;
    __shared__ u16 kl[512];
    __shared__ int ntS;
    int tid = threadIdx.x;
    if (tid == 0) ntS = nkt[b];
    kl[tid] = kidxg[b * 512 + tid];
    kl[tid + 256] = kidxg[b * 512 + tid + 256];
    __syncthreads();
    int nkp = ntS * 32;
    for (int rq = 0; rq < 8; ++rq) {
        int q = q0 + rq;
        long rowoff = ((long)b * 512 + q) * 512;
        for (int j = tid; j < nkp; j += 256) {
            float d = ldin(dist, rowoff + kl[j], bf);
            int v = (int)(d * 10.0f);
            v = v < 0 ? 0 : (v > 49 ? 49 : v);
            binsc[((size_t)b * 512 + q) * 512 + j] = (unsigned char)(v << 2);
        }
    }
}

// ===== MFMA GEMM 64-row tile + optional fused LN and/or final-output copy ======
__global__ __launch_bounds__(256, 2) void mfma_gemm64_kernel(
    const u16* __restrict__ A, const u16* __restrict__ WT,
    const void* __restrict__ braw, long bOff, float* __restrict__ C,
    int K, int resid, const int* flagp,
    const void* lnG, const void* lnB, long lnOff, u16* hnout, void* outp) {
    __shared__ __align__(16) u16 As[64][40];
    __shared__ __align__(16) u16 Bs[128][40];
    __shared__ float Ct[64][128];
    int tid = threadIdx.x;
    int m0 = blockIdx.x * 64;
    int wave = tid >> 6, lane = tid & 63;
    int wm = (wave >> 1) * 32, wn = (wave & 1) * 64;
    int q = lane >> 4, ln = lane & 15;
    f32x4 zero = {0.f, 0.f, 0.f, 0.f};
    f32x4 acc[2][4];
#pragma unroll
    for (int i = 0; i < 2; ++i)
#pragma unroll
        for (int j = 0; j < 4; ++j) acc[i][j] = zero;
    int sar = tid >> 2, sac = (tid & 3) * 8;
    int sbr = tid >> 1, sbc = (tid & 1) * 16;
    const u16* Ap = A + (size_t)(m0 + sar) * K + sac;
    const u16* Bp = WT + (size_t)sbr * K + sbc;
    for (int k0 = 0; k0 < K; k0 += 32) {
        uint4 av = *(const uint4*)(Ap + k0);
        uint4 b0 = *(const uint4*)(Bp + k0);
        uint4 b1 = *(const uint4*)(Bp + k0 + 8);
        *(uint4*)&As[sar][sac] = av;
        *(uint4*)&Bs[sbr][sbc] = b0; *(uint4*)&Bs[sbr][sbc + 8] = b1;
        __syncthreads();
        short8 af[2], bfv[4];
#pragma unroll
        for (int t = 0; t < 2; ++t) af[t] = *(const short8*)&As[wm + t * 16 + ln][q * 8];
#pragma unroll
        for (int t = 0; t < 4; ++t) bfv[t] = *(const short8*)&Bs[wn + t * 16 + ln][q * 8];
#pragma unroll
        for (int ti = 0; ti < 2; ++ti)
#pragma unroll
            for (int tj = 0; tj < 4; ++tj)
                acc[ti][tj] = __builtin_amdgcn_mfma_f32_16x16x32_bf16(
                    af[ti], bfv[tj], acc[ti][tj], 0, 0, 0);
        __syncthreads();
    }
    int bf = *flagp;
#pragma unroll
    for (int tj = 0; tj < 4; ++tj) {
        int n = wn + tj * 16 + ln;
        float bias = ldin(braw, bOff + n, bf);
#pragma unroll
        for (int ti = 0; ti < 2; ++ti)
#pragma unroll
            for (int r = 0; r < 4; ++r) {
                int m = m0 + wm + ti * 16 + q * 4 + r;
                float v = acc[ti][tj][r] + bias;
                float* dst = C + (size_t)m * 128 + n;
                if (resid) v += *dst;
                *dst = v;
                Ct[m - m0][n] = v;
                if (outp) {
                    if (bf) ((u16*)outp)[(size_t)m * 128 + n] = f2bf(v);
                    else ((float*)outp)[(size_t)m * 128 + n] = v;
                }
            }
    }
    if (hnout) {
        __syncthreads();
        float gg0 = ldin(lnG, lnOff + lane, bf);
        float gg1 = ldin(lnG, lnOff + lane + 64, bf);
        float bb0 = ldin(lnB, lnOff + lane, bf);
        float bb1 = ldin(lnB, lnOff + lane + 64, bf);
        for (int rr = 0; rr < 16; ++rr) {
            int row = wave * 16 + rr;
            float x0 = Ct[row][lane], x1 = Ct[row][lane + 64];
            float s = x0 + x1, s2v = x0 * x0 + x1 * x1;
#pragma unroll
            for (int o = 32; o; o >>= 1) {
                s += __shfl_xor(s, o);
                s2v += __shfl_xor(s2v, o);
            }
            float mu = s * (1.0f / 128.0f);
            float var = fmaxf(s2v * (1.0f / 128.0f) - mu * mu, 0.0f);
            float rstd = rsqrtf(var + 1e-5f);
            int m = m0 + row;
            hnout[(size_t)m * 128 + lane]      = f2bf((x0 - mu) * rstd * gg0 + bb0);
            hnout[(size_t)m * 128 + lane + 64] = f2bf((x1 - mu) * rstd * gg1 + bb1);
        }
    }
}

// QKV fused, 64-row tiles: grid (256, 3); outputs f16 bits; Q pre-scaled by 0.25
__global__ __launch_bounds__(256, 2) void qkv_mfma_kernel(
    const u16* __restrict__ A, const u16* __restrict__ qkvT_l,
    const void* bqr, const void* bkr, const void* bvr, long bOff,
    u16* __restrict__ Qo, u16* __restrict__ Ko, u16* __restrict__ Vo,
    const int* flagp) {
    int sel = blockIdx.y;
    const u16* WT = qkvT_l + (size_t)sel * 16384;
    const void* braw = sel == 0 ? bqr : (sel == 1 ? bkr : bvr);
    u16* C = sel == 0 ? Qo : (sel == 1 ? Ko : Vo);
    float scale = sel == 0 ? 0.25f : 1.0f;
    __shared__ __align__(16) u16 As[64][40];
    __shared__ __align__(16) u16 Bs[128][40];
    int tid = threadIdx.x;
    int m0 = blockIdx.x * 64;
    int wave = tid >> 6, lane = tid & 63;
    int wm = (wave >> 1) * 32, wn = (wave & 1) * 64;
    int q = lane >> 4, ln = lane & 15;
    f32x4 zero = {0.f, 0.f, 0.f, 0.f};
    f32x4 acc[2][4];
#pragma unroll
    for (int i = 0; i < 2; ++i)
#pragma unroll
        for (int j = 0; j < 4; ++j) acc[i][j] = zero;
    int sar = tid >> 2, sac = (tid & 3) * 8;
    int sbr = tid >> 1, sbc = (tid & 1) * 16;
    const u16* Ap = A + (size_t)(m0 + sar) * 128 + sac;
    const u16* Bp = WT + (size_t)sbr * 128 + sbc;
#pragma unroll
    for (int k0 = 0; k0 < 128; k0 += 32) {
        uint4 av = *(const uint4*)(Ap + k0);
        uint4 b0 = *(const uint4*)(Bp + k0);
        uint4 b1 = *(const uint4*)(Bp + k0 + 8);
        *(uint4*)&As[sar][sac] = av;
        *(uint4*)&Bs[sbr][sbc] = b0; *(uint4*)&Bs[sbr][sbc + 8] = b1;
        __syncthreads();
        short8 af[2], bfv[4];
#pragma unroll
        for (int t = 0; t < 2; ++t) af[t] = *(const short8*)&As[wm + t * 16 + ln][q * 8];
#pragma unroll
        for (int t = 0; t < 4; ++t) bfv[t] = *(const short8*)&Bs[wn + t * 16 + ln][q * 8];
#pragma unroll
        for (int ti = 0; ti < 2; ++ti)
#pragma unroll
            for (int tj = 0; tj < 4; ++tj)
                acc[ti][tj] = __builtin_amdgcn_mfma_f32_16x16x32_bf16(
                    af[ti], bfv[tj], acc[ti][tj], 0, 0, 0);
        __syncthreads();
    }
    int bf = *flagp;
#pragma unroll
    for (int tj = 0; tj < 4; ++tj) {
        int n = wn + tj * 16 + ln;
        float bias = ldin(braw, bOff + n, bf);
#pragma unroll
        for (int ti = 0; ti < 2; ++ti)
#pragma unroll
            for (int r = 0; r < 4; ++r) {
                int m = m0 + wm + ti * 16 + q * 4 + r;
                C[(size_t)m * 128 + n] = f2h((acc[ti][tj][r] + bias) * scale);
            }
    }
}

// GLU-FF1 (unchanged)
__global__ __launch_bounds__(256, 2) void glu_mfma_kernel(
    const u16* __restrict__ A, const u16* __restrict__ f1T_l,
    const void* __restrict__ braw, long bOff, u16* __restrict__ Vout,
    const int* flagp) {
    __shared__ __align__(16) u16 As[128][40];
    __shared__ __align__(16) u16 Ba[64][40];
    __shared__ __align__(16) u16 Bb[64][40];
    int tid = threadIdx.x;
    int m0 = blockIdx.x * 128, n0 = blockIdx.y * 64;
    int wave = tid >> 6, lane = tid & 63;
    int wm = (wave >> 1) * 64, wn = (wave & 1) * 32;
    int q = lane >> 4, ln = lane & 15;
    f32x4 zero = {0.f, 0.f, 0.f, 0.f};
    f32x4 accA[4][2], accB[4][2];
#pragma unroll
    for (int i = 0; i < 4; ++i)
#pragma unroll
        for (int j = 0; j < 2; ++j) { accA[i][j] = zero; accB[i][j] = zero; }
    int sr = tid >> 1, sc = (tid & 1) * 16;
    const u16* Ap = A + (size_t)(m0 + sr) * 128 + sc;
    const u16* BpA = f1T_l + (size_t)(n0 + sr) * 128 + sc;
    const u16* BpB = f1T_l + (size_t)(512 + n0 + (sr - 64)) * 128 + sc;
#pragma unroll
    for (int k0 = 0; k0 < 128; k0 += 32) {
        uint4 a0 = *(const uint4*)(Ap + k0);
        uint4 a1 = *(const uint4*)(Ap + k0 + 8);
        *(uint4*)&As[sr][sc] = a0; *(uint4*)&As[sr][sc + 8] = a1;
        if (sr < 64) {
            uint4 w0 = *(const uint4*)(BpA + k0);
            uint4 w1 = *(const uint4*)(BpA + k0 + 8);
            *(uint4*)&Ba[sr][sc] = w0; *(uint4*)&Ba[sr][sc + 8] = w1;
        } else {
            uint4 w0 = *(const uint4*)(BpB + k0);
            uint4 w1 = *(const uint4*)(BpB + k0 + 8);
            *(uint4*)&Bb[sr - 64][sc] = w0; *(uint4*)&Bb[sr - 64][sc + 8] = w1;
        }
        __syncthreads();
        short8 af[4], ba[2], bb[2];
#pragma unroll
        for (int t = 0; t < 4; ++t) af[t] = *(const short8*)&As[wm + t * 16 + ln][q * 8];
#pragma unroll
        for (int t = 0; t < 2; ++t) {
            ba[t] = *(const short8*)&Ba[wn + t * 16 + ln][q * 8];
            bb[t] = *(const short8*)&Bb[wn + t * 16 + ln][q * 8];
        }
#pragma unroll
        for (int ti = 0; ti < 4; ++ti)
#pragma unroll
            for (int tj = 0; tj < 2; ++tj) {
                accA[ti][tj] = __builtin_amdgcn_mfma_f32_16x16x32_bf16(
                    af[ti], ba[tj], accA[ti][tj], 0, 0, 0);
                accB[ti][tj] = __builtin_amdgcn_mfma_f32_16x16x32_bf16(
                    af[ti], bb[tj], accB[ti][tj], 0, 0, 0);
            }
        __syncthreads();
    }
    int bf = *flagp;
#pragma unroll
    for (int tj = 0; tj < 2; ++tj) {
        int n = n0 + wn + tj * 16 + ln;
        float biasA = ldin(braw, bOff + n, bf);
        float biasB = ldin(braw, bOff + 512 + n, bf);
#pragma unroll
        for (int ti = 0; ti < 4; ++ti)
#pragma unroll
            for (int r = 0; r < 4; ++r) {
                int m = m0 + wm + ti * 16 + q * 4 + r;
                float ua = accA[ti][tj][r] + biasA;
                float ub = accB[ti][tj][r] + biasB;
                Vout[(size_t)m * 512 + n] = f2bf(ua / (1.0f + __expf(-ub)));
            }
    }
}

// ========== attention v6: 16x16x16 MFMA, zero P round-trip, mask-compressed ==========
// S^T = K Q^T via mfma_f32_16x16x16_f16 (K-dim = HD = 16, all lanes used).
// KEY TRICK: S^T's C-layout (key=quad*4+r, q=ln) IS the A-frag layout
// A[m=ln][k=quad*4+j] for the PV mfma — exp(S^T) feeds PV directly in regs.
// LDS 37.1 KB -> 4 blocks/CU. Bias via ds_bpermute LUT; fixed-shift softmax.
__global__ __launch_bounds__(256, 4) void attn_kernel(
    const u16* __restrict__ Qh, const u16* __restrict__ Kh,
    const u16* __restrict__ Vh, const unsigned char* __restrict__ binsc,
    const u16* __restrict__ kidxg, const int* __restrict__ nktp,
    const unsigned* __restrict__ tmaskp, const float* __restrict__ deL,
    const float* __restrict__ abL, u16* __restrict__ out) {
    // de-swizzle: heads of one (b,qq) share id%8 -> same XCD L2 for binsc
    int id = blockIdx.x;
    int c = id & 7, t5 = id >> 3;
    int nh = t5 & 7;
    int pair = ((t5 >> 3) << 3) | c;
    int b = pair >> 2, qq = pair & 3;

    __shared__ __align__(16) u16 KsF[512 * 20];  // K rows, stride 20 f16 (40B), 20 KB
    __shared__ __align__(16) u16 VT[16 * 520];   // V^T rows 520 f16, 16.6 KB

    int tid = threadIdx.x;
    int nt = __builtin_amdgcn_readfirstlane(nktp[b]);
    int nkp = nt * 32;
    const u16* Kp = Kh + (size_t)(b * Nq) * Hq + nh * HDq;
    const u16* Vp = Vh + (size_t)(b * Nq) * Hq + nh * HDq;
    for (int r = tid; r < nkp; r += 256) {
        int row = kidxg[b * 512 + r];
        uint4 k0v = *(const uint4*)(Kp + (size_t)row * Hq);
        uint4 k1v = *(const uint4*)(Kp + (size_t)row * Hq + 8);
        *(uint2*)&KsF[r * 20]      = make_uint2(k0v.x, k0v.y);
        *(uint2*)&KsF[r * 20 + 4]  = make_uint2(k0v.z, k0v.w);
        *(uint2*)&KsF[r * 20 + 8]  = make_uint2(k1v.x, k1v.y);
        *(uint2*)&KsF[r * 20 + 12] = make_uint2(k1v.z, k1v.w);
        uint4 v0 = *(const uint4*)(Vp + (size_t)row * Hq);
        uint4 v1 = *(const uint4*)(Vp + (size_t)row * Hq + 8);
        u16 vv[16];
        *(uint4*)&vv[0] = v0; *(uint4*)&vv[8] = v1;
#pragma unroll
        for (int d = 0; d < 16; ++d) VT[d * 520 + r] = vv[d];
    }
    __syncthreads();

    int wave = tid >> 6, lane = tid & 63;
    int quad = lane >> 4, ln = lane & 15;
    int q0w = qq * 128 + wave * 32;

    float tblf = (lane < 50) ? deL[lane * NHq + nh] + abL[nh] : 0.0f;
    int tbli = __float_as_int(tblf);
    unsigned tl = tmaskp[b * 16 + nt - 1];

    // Q B-frags for 16x16x16: B[n=q][k=d=quad*4+j] -> uint2 global load
    half4 qf[2];
#pragma unroll
    for (int t = 0; t < 2; ++t) {
        uint2 qv = *(const uint2*)(Qh + (size_t)(b * Nq + q0w + t * 16 + ln) * Hq
                                   + nh * HDq + quad * 4);
        qf[t] = *(half4*)&qv;
    }

    f32x4 zero = {0.f, 0.f, 0.f, 0.f};
    f32x4 acc[2] = {zero, zero};
    float zp[2] = {0.f, 0.f};
    const _Float16* KsH = (const _Float16*)KsF;
    const _Float16* VTH = (const _Float16*)VT;
    const unsigned char* brow0 = binsc + ((size_t)b * 512 + (q0w + ln)) * 512;
    const unsigned char* brow1 = brow0 + (size_t)16 * 512;

    // prefetch kt=0 bias-byte dwords
    unsigned pb00 = *(const unsigned*)(brow0 + quad * 4);
    unsigned pb01 = *(const unsigned*)(brow0 + 16 + quad * 4);
    unsigned pb10 = *(const unsigned*)(brow1 + quad * 4);
    unsigned pb11 = *(const unsigned*)(brow1 + 16 + quad * 4);

    for (int kt = 0; kt < nt; ++kt) {
        int k0 = kt * 32;
        unsigned w = (kt == nt - 1) ? tl : 0u;
        unsigned cb00 = pb00, cb01 = pb01, cb10 = pb10, cb11 = pb11;
        if (kt < nt - 1) {
            pb00 = *(const unsigned*)(brow0 + k0 + 32 + quad * 4);
            pb01 = *(const unsigned*)(brow0 + k0 + 48 + quad * 4);
            pb10 = *(const unsigned*)(brow1 + k0 + 32 + quad * 4);
            pb11 = *(const unsigned*)(brow1 + k0 + 48 + quad * 4);
        }
        // K A-frags: A[m=key-in-tile=ln][k=d=quad*4+j]
        half4 ka0 = *(const half4*)(KsH + (size_t)(k0 + ln) * 20 + quad * 4);
        half4 ka1 = *(const half4*)(KsH + (size_t)(k0 + 16 + ln) * 20 + quad * 4);
        // V B-frags: B[n=d=ln][k=key=quad*4+j]
        half4 vb0 = *(const half4*)(VTH + ln * 520 + k0 + quad * 4);
        half4 vb1 = *(const half4*)(VTH + ln * 520 + k0 + 16 + quad * 4);
#pragma unroll
        for (int t = 0; t < 2; ++t) {
            unsigned bw0 = t == 0 ? cb00 : cb10;
            unsigned bw1 = t == 0 ? cb01 : cb11;
            f32x4 s0 = __builtin_amdgcn_mfma_f32_16x16x16f16(ka0, qf[t], zero, 0, 0, 0);
            f32x4 s1 = __builtin_amdgcn_mfma_f32_16x16x16f16(ka1, qf[t], zero, 0, 0, 0);
            float p[8];
#pragma unroll
            for (int r = 0; r < 4; ++r) {
                float bias = __int_as_float(__builtin_amdgcn_ds_bpermute(
                    (int)((bw0 >> (8 * r)) & 0xFFu), tbli));
                float sc = s0[r] + bias;
                bool m = (w >> (quad * 4 + r)) & 1u;
                p[r] = m ? 0.0f : __expf(sc);
            }
#pragma unroll
            for (int r = 0; r < 4; ++r) {
                float bias = __int_as_float(__builtin_amdgcn_ds_bpermute(
                    (int)((bw1 >> (8 * r)) & 0xFFu), tbli));
                float sc = s1[r] + bias;
                bool m = (w >> (16 + quad * 4 + r)) & 1u;
                p[4 + r] = m ? 0.0f : __expf(sc);
            }
            zp[t] += ((p[0] + p[1]) + (p[2] + p[3])) +
                     ((p[4] + p[5]) + (p[6] + p[7]));
            // exp(S^T) is already in PV A-frag layout: pack & feed directly
            uint2 pw0 = make_uint2(pk2h(p[0], p[1]), pk2h(p[2], p[3]));
            uint2 pw1 = make_uint2(pk2h(p[4], p[5]), pk2h(p[6], p[7]));
            half4 pa0 = *(half4*)&pw0;
            half4 pa1 = *(half4*)&pw1;
            acc[t] = __builtin_amdgcn_mfma_f32_16x16x16f16(pa0, vb0, acc[t], 0, 0, 0);
            acc[t] = __builtin_amdgcn_mfma_f32_16x16x16f16(pa1, vb1, acc[t], 0, 0, 0);
        }
    }
#pragma unroll
    for (int t = 0; t < 2; ++t) {
        zp[t] += __shfl_xor(zp[t], 16);
        zp[t] += __shfl_xor(zp[t], 32);
    }
    // acc C-layout: row = q = quad*4+r, col = d = ln
#pragma unroll
    for (int t = 0; t < 2; ++t) {
#pragma unroll
        for (int r = 0; r < 4; ++r) {
            float zz = __shfl(zp[t], quad * 4 + r);
            float val = acc[t][r] / fmaxf(zz, 1e-35f);
            int qrow = q0w + t * 16 + quad * 4 + r;
            out[(size_t)(b * Nq + qrow) * Hq + nh * HDq + ln] = f2bf(val);
        }
    }
}

extern "C" void kernel_launch(void* const* d_in, const int* in_sizes, int n_in,
                              void* d_out, int out_size, void* d_ws, size_t ws_size,
                              hipStream_t stream) {
    const void* x  = d_in[0];
    const void* dist = d_in[1];
    const void* mask = d_in[2];
    const void* Wq = d_in[3];  const void* bq = d_in[4];
    const void* Wk = d_in[5];  const void* bk = d_in[6];
    const void* Wv = d_in[7];  const void* bv = d_in[8];
    const void* Wo = d_in[9];  const void* bo = d_in[10];
    const void* de = d_in[11]; const void* ab = d_in[12];
    const void* g1 = d_in[13]; const void* b1 = d_in[14];
    const void* g2 = d_in[15]; const void* b2 = d_in[16];
    const void* Wf1 = d_in[17]; const void* bf1 = d_in[18];
    const void* Wf2 = d_in[19]; const void* bf2 = d_in[20];

    char* ws = (char*)d_ws;
    const size_t OFF_DE   = 64;
    const size_t OFF_AB   = 5120;
    const size_t OFF_BINS = 8192;                    // binsc 8,388,608
    const size_t OFF_MSK  = OFF_BINS + 8388608;      // mbits 2 KB (4096 res)
    const size_t OFF_KIDX = OFF_MSK + 4096;          // 32768
    const size_t OFF_NKT  = OFF_KIDX + 32768;        // 256
    const size_t OFF_TM   = OFF_NKT + 256;           // 2048
    const size_t OFF_H    = OFF_TM + 4096;           // f32 8,388,608
    const size_t OFF_QKV  = OFF_H + 8388608;         // Qh,Kh,Vh f16 | vglu u16 16MB
    const size_t OFF_HN   = OFF_QKV + 25165824;      // u16 4,194,304
    const size_t OFF_ATT  = OFF_HN + 4194304;        // u16 4,194,304
    const size_t OFF_WT   = OFF_ATT + 4194304;       // u16 1,572,864
    const size_t NEEDED   = OFF_WT + 1572864;
    if (ws_size < NEEDED) return;

    int* flag = (int*)ws;
    float* deF = (float*)(ws + OFF_DE);
    float* abF = (float*)(ws + OFF_AB);
    unsigned char* binsc = (unsigned char*)(ws + OFF_BINS);
    unsigned* mbits = (unsigned*)(ws + OFF_MSK);
    u16* kidxg = (u16*)(ws + OFF_KIDX);
    int* nkt = (int*)(ws + OFF_NKT);
    unsigned* tmask = (unsigned*)(ws + OFF_TM);
    float* h = (float*)(ws + OFF_H);
    u16* Qh = (u16*)(ws + OFF_QKV);
    u16* Kh = Qh + 2097152;
    u16* Vh = Qh + 2 * 2097152;
    u16* vglu = (u16*)(ws + OFF_QKV);
    u16* hn = (u16*)(ws + OFF_HN);
    u16* att = (u16*)(ws + OFF_ATT);
    u16* qkvT = (u16*)(ws + OFF_WT);
    u16* oT  = qkvT + 147456;
    u16* f1T = oT + 49152;
    u16* f2T = f1T + 393216;

    megaprep_kernel<<<4865, 256, 0, stream>>>(
        x, de, ab, mask, flag, deF, abF, mbits, kidxg, nkt, tmask,
        h, hn, g1, b1, Wq, Wk, Wv, Wo, Wf1, Wf2, qkvT, oT, f1T, f2T);
    dim3 gbc(64, 32);
    binsc_kernel<<<gbc, 256, 0, stream>>>(dist, kidxg, nkt, binsc, flag);

    dim3 gqkv(256, 3);
    dim3 gglu(128, 8);
    for (int l = 0; l < 3; ++l) {
        qkv_mfma_kernel<<<gqkv, 256, 0, stream>>>(hn, qkvT + (size_t)l * 49152,
                                                  bq, bk, bv, (long)l * Hq,
                                                  Qh, Kh, Vh, flag);
        attn_kernel<<<1024, 256, 0, stream>>>(Qh, Kh, Vh, binsc, kidxg, nkt, tmask,
                                              deF + (long)l * 400, abF + (long)l * 8, att);
        // o-proj + residual + fused LN2 -> h, hn
        mfma_gemm64_kernel<<<256, 256, 0, stream>>>(att, oT + (size_t)l * 16384,
                                                    bo, (long)l * Hq, h, 128, 1, flag,
                                                    g2, b2, (long)l * Hq, hn, nullptr);
        glu_mfma_kernel<<<gglu, 256, 0, stream>>>(hn, f1T + (size_t)l * 131072,
                                                  bf1, (long)l * 1024, vglu, flag);
        if (l < 2) {
            mfma_gemm64_kernel<<<256, 256, 0, stream>>>(vglu, f2T + (size_t)l * 65536,
                                                        bf2, (long)l * Hq, h, 512, 1, flag,
                                                        g1, b1, (long)(l + 1) * Hq, hn,
                                                        nullptr);
        } else {
            mfma_gemm64_kernel<<<256, 256, 0, stream>>>(vglu, f2T + (size_t)l * 65536,
                                                        bf2, (long)l * Hq, h, 512, 1, flag,
                                                        nullptr, nullptr, 0, nullptr,
                                                        d_out);
        }
    }
}

// Round 9
// 409.925 us; speedup vs baseline: 1.0357x; 1.0357x over previous
//
#include <hip/hip_runtime.h>
#include <stdint.h>

#define Bq 32
#define Nq 512
#define Hq 128
#define NHq 8
#define HDq 16
#define Mq (Bq * Nq)   // 16384

typedef unsigned short u16;
typedef __attribute__((ext_vector_type(8))) short short8;
typedef __attribute__((ext_vector_type(4))) _Float16 half4;
typedef __attribute__((ext_vector_type(2))) __fp16 fp16x2;
typedef __attribute__((ext_vector_type(4))) float f32x4;

// ---------- dtype-flex helpers (flag: 1 = inputs are bf16, 0 = f32) ----------
__device__ __forceinline__ float bf2f(u16 v) {
    return __uint_as_float(((unsigned int)v) << 16);
}
__device__ __forceinline__ float ldin(const void* p, long idx, int bf) {
    if (bf) return bf2f(((const u16*)p)[idx]);
    return ((const float*)p)[idx];
}
__device__ __forceinline__ u16 f2bf(float v) {   // RNE
    unsigned int u = __float_as_uint(v);
    return (u16)((u + 0x7FFFu + ((u >> 16) & 1u)) >> 16);
}
__device__ __forceinline__ u16 f2h(float v) {    // f32 -> f16 bits (RNE)
    _Float16 h = (_Float16)v;
    return *(u16*)&h;
}
__device__ __forceinline__ unsigned pk2h(float a, float b) {  // packed f16 pair bits
    fp16x2 c = __builtin_amdgcn_cvt_pkrtz(a, b);
    return *(unsigned*)&c;
}

// ---------- merged prep: dtype detect + small converts + mask bit-words ----------
__global__ void prep_kernel(const void* xraw, const void* de, const void* ab,
                            const void* mraw, int* flag, float* deo, float* abo,
                            unsigned* mbits, int n) {
    __shared__ int cnt, orA, orB, orC, orD;
    int tid = threadIdx.x;
    if (tid == 0) { cnt = 0; orA = 0; orB = 0; orC = 0; orD = 0; }
    __syncthreads();
    const u16* u = (const u16*)xraw;
    int good = 0;
    for (int i = tid; i < 1024; i += 256) {
        u16 v = u[i];
        int e = (v >> 7) & 0xFF;
        if (v == 0 || (e >= 90 && e <= 141)) good++;
    }
    atomicAdd(&cnt, good);
    // vectorized mask encoding scan over first n bytes
    const uint4* p4 = (const uint4*)mraw;
    unsigned a = 0, b = 0, c = 0, d = 0;
    for (int i = tid; i < n / 16; i += 256) {
        uint4 w = p4[i];
        unsigned all = w.x | w.y | w.z | w.w;
        a |= all & 0xFEFEFEFEu;
        b |= all & 0x0000FF00u;
        c |= all & 0xFFFFFF00u;
        d |= w.y | w.w;
    }
    if (a) atomicOr(&orA, 1);
    if (b) atomicOr(&orB, 1);
    if (c) atomicOr(&orC, 1);
    if (d) atomicOr(&orD, 1);
    __syncthreads();
    int bf = (cnt >= 900);
    if (tid == 0) *flag = bf;
    int mode;  // 0 bool8, 1 int32, 2 int64, 3 bf16, 4 f32
    if (orA) mode = orB ? 3 : 4;
    else if (orC) mode = 0;
    else mode = orD ? 1 : 2;
    for (int i = tid; i < 1200; i += 256) deo[i] = ldin(de, i, bf);
    if (tid < 24) abo[tid] = ldin(ab, tid, bf);
    const unsigned char* p = (const unsigned char*)mraw;
    for (int wI = tid; wI < n / 32; wI += 256) {
        unsigned word = 0;
        for (int j = 0; j < 32; ++j) {
            int i = wI * 32 + j;
            int v;
            switch (mode) {
                case 0: v = p[i]; break;
                case 1: v = ((const int*)p)[i]; break;
                case 2: v = (int)((const long long*)p)[i]; break;
                case 3: v = ((const u16*)p)[i] != 0; break;
                default: v = (((const float*)p)[i] != 0.0f); break;
            }
            if (v) word |= 1u << j;
        }
        mbits[wI] = word;
    }
}

// ---------- kprep: per-batch compressed unmasked-k index list ----------
__global__ void kprep_kernel(const unsigned* __restrict__ mbits,
                             u16* __restrict__ kidxg, int* __restrict__ nkt,
                             unsigned* __restrict__ tmask) {
    int b = blockIdx.x;
    int lane = threadIdx.x & 63;
    int pos_base = 0;
    for (int w = 0; w < 8; ++w) {
        unsigned lo = mbits[b * 16 + 2 * w], hi = mbits[b * 16 + 2 * w + 1];
        unsigned long long word = ((unsigned long long)hi << 32) | lo;
        unsigned long long un = ~word;   // 1 = unmasked
        int bit = (int)((un >> lane) & 1ull);
        unsigned long long before = un & ((1ull << lane) - 1ull);
        int pos = pos_base + __popcll(before);
        if (bit) kidxg[b * 512 + pos] = (u16)(w * 64 + lane);
        pos_base += __popcll(un);
    }
    int nk = pos_base;
    int nkp = (nk + 31) & ~31;
    if (nkp == 0) nkp = 32;
    int nt = nkp >> 5;
    for (int j = nk + lane; j < nkp; j += 64) kidxg[b * 512 + j] = 0;
    if (lane == 0) {
        nkt[b] = nt;
        for (int t = 0; t < 16; ++t) tmask[b * 16 + t] = 0;
        int rem = nk & 31;
        if (rem) tmask[b * 16 + nt - 1] = 0xFFFFFFFFu << rem;
        if (nk == 0) tmask[b * 16] = 0xFFFFFFFFu;
    }
}

// ---------- binsc: compressed, pre-scaled (x4) bin bytes from dist ----------
__global__ __launch_bounds__(256) void binsc_kernel(
    const void* __restrict__ dist, const u16* __restrict__ kidxg,
    const int* __restrict__ nkt, unsigned char* __restrict__ binsc,
    const int* flagp) {
    int bf = *flagp;
    int b = blockIdx.y;
    int q0 = blockIdx.x * 8;
    __shared__ u16 kl[512];
    __shared__ int ntS;
    int tid = threadIdx.x;
    if (tid == 0) ntS = nkt[b];
    kl[tid] = kidxg[b * 512 + tid];
    kl[tid + 256] = kidxg[b * 512 + tid + 256];
    __syncthreads();
    int nkp = ntS * 32;
    for (int rq = 0; rq < 8; ++rq) {
        int q = q0 + rq;
        long rowoff = ((long)b * 512 + q) * 512;
        for (int j = tid; j < nkp; j += 256) {
            float d = ldin(dist, rowoff + kl[j], bf);
            int v = (int)(d * 10.0f);
            v = v < 0 ? 0 : (v > 49 ? 49 : v);
            binsc[((size_t)b * 512 + q) * 512 + j] = (unsigned char)(v << 2);
        }
    }
}

// ---------- init + first LN: x -> h (f32) and hn = LN(x) (bf16) ----------
__global__ __launch_bounds__(256) void init_ln_kernel(
    const void* x, float* __restrict__ h, u16* __restrict__ hn,
    const void* graw, const void* braw, const int* flagp) {
    int bf = *flagp;
    int row = blockIdx.x * 4 + (threadIdx.x >> 6);
    int lane = threadIdx.x & 63;
    float x0 = ldin(x, (long)row * Hq + lane, bf);
    float x1 = ldin(x, (long)row * Hq + lane + 64, bf);
    h[(size_t)row * Hq + lane] = x0;
    h[(size_t)row * Hq + lane + 64] = x1;
    float s = x0 + x1, s2 = x0 * x0 + x1 * x1;
#pragma unroll
    for (int o = 32; o; o >>= 1) {
        s += __shfl_xor(s, o);
        s2 += __shfl_xor(s2, o);
    }
    float mu = s * (1.0f / 128.0f);
    float var = fmaxf(s2 * (1.0f / 128.0f) - mu * mu, 0.0f);
    float rr = rsqrtf(var + 1e-5f);
    float g0 = ldin(graw, lane, bf), g1v = ldin(graw, lane + 64, bf);
    float b0 = ldin(braw, lane, bf), b1v = ldin(braw, lane + 64, bf);
    hn[(size_t)row * Hq + lane]      = f2bf((x0 - mu) * rr * g0 + b0);
    hn[(size_t)row * Hq + lane + 64] = f2bf((x1 - mu) * rr * g1v + b1v);
}

// ---------- weight transpose: W[K][N] -> WT[N][K] bf16 ----------
__global__ __launch_bounds__(256) void wtrans_kernel(
    const void* Wqr, const void* Wkr, const void* Wvr, const void* Wor,
    const void* Wf1r, const void* Wf2r,
    u16* qkvT, u16* oT, u16* f1T, u16* f2T, const int* flagp) {
    int bf = *flagp;
    int bid = blockIdx.x;
    int l = bid >> 8, r = bid & 255;
    const void* src; u16* dst; long soff, doff; int Kd, Nd, t;
    if (r < 64) {
        int mat = r >> 4; t = r & 15; Kd = 128; Nd = 128;
        soff = (long)l * 16384;
        if (mat == 0)      { src = Wqr; dst = qkvT; doff = (long)l * 49152; }
        else if (mat == 1) { src = Wkr; dst = qkvT; doff = (long)l * 49152 + 16384; }
        else if (mat == 2) { src = Wvr; dst = qkvT; doff = (long)l * 49152 + 32768; }
        else               { src = Wor; dst = oT;   doff = (long)l * 16384; }
    } else if (r < 192) {
        t = r - 64; Kd = 128; Nd = 1024;
        src = Wf1r; soff = (long)l * 131072; dst = f1T; doff = (long)l * 131072;
    } else {
        t = r - 192; Kd = 512; Nd = 128;
        src = Wf2r; soff = (long)l * 65536; dst = f2T; doff = (long)l * 65536;
    }
    int ntile = Nd >> 5;
    int tk = t / ntile, tn = t % ntile;
    __shared__ u16 Ts[32][33];
    int rr = threadIdx.x >> 3, cc0 = (threadIdx.x & 7) * 4;
#pragma unroll
    for (int i = 0; i < 4; ++i) {
        long idx = soff + (long)(tk * 32 + rr) * Nd + tn * 32 + cc0 + i;
        Ts[rr][cc0 + i] = f2bf(ldin(src, idx, bf));
    }
    __syncthreads();
#pragma unroll
    for (int i = 0; i < 4; ++i) {
        long idx = doff + (long)(tn * 32 + rr) * Kd + tk * 32 + cc0 + i;
        dst[idx] = Ts[cc0 + i][rr];
    }
}

// ===== MFMA GEMM 64-row tile + optional fused LN and/or final-output copy ======
__global__ __launch_bounds__(256, 2) void mfma_gemm64_kernel(
    const u16* __restrict__ A, const u16* __restrict__ WT,
    const void* __restrict__ braw, long bOff, float* __restrict__ C,
    int K, int resid, const int* flagp,
    const void* lnG, const void* lnB, long lnOff, u16* hnout, void* outp) {
    __shared__ __align__(16) u16 As[64][40];
    __shared__ __align__(16) u16 Bs[128][40];
    __shared__ float Ct[64][128];
    int tid = threadIdx.x;
    int m0 = blockIdx.x * 64;
    int wave = tid >> 6, lane = tid & 63;
    int wm = (wave >> 1) * 32, wn = (wave & 1) * 64;
    int q = lane >> 4, ln = lane & 15;
    f32x4 zero = {0.f, 0.f, 0.f, 0.f};
    f32x4 acc[2][4];
#pragma unroll
    for (int i = 0; i < 2; ++i)
#pragma unroll
        for (int j = 0; j < 4; ++j) acc[i][j] = zero;
    int sar = tid >> 2, sac = (tid & 3) * 8;
    int sbr = tid >> 1, sbc = (tid & 1) * 16;
    const u16* Ap = A + (size_t)(m0 + sar) * K + sac;
    const u16* Bp = WT + (size_t)sbr * K + sbc;
    for (int k0 = 0; k0 < K; k0 += 32) {
        uint4 av = *(const uint4*)(Ap + k0);
        uint4 b0 = *(const uint4*)(Bp + k0);
        uint4 b1 = *(const uint4*)(Bp + k0 + 8);
        *(uint4*)&As[sar][sac] = av;
        *(uint4*)&Bs[sbr][sbc] = b0; *(uint4*)&Bs[sbr][sbc + 8] = b1;
        __syncthreads();
        short8 af[2], bfv[4];
#pragma unroll
        for (int t = 0; t < 2; ++t) af[t] = *(const short8*)&As[wm + t * 16 + ln][q * 8];
#pragma unroll
        for (int t = 0; t < 4; ++t) bfv[t] = *(const short8*)&Bs[wn + t * 16 + ln][q * 8];
#pragma unroll
        for (int ti = 0; ti < 2; ++ti)
#pragma unroll
            for (int tj = 0; tj < 4; ++tj)
                acc[ti][tj] = __builtin_amdgcn_mfma_f32_16x16x32_bf16(
                    af[ti], bfv[tj], acc[ti][tj], 0, 0, 0);
        __syncthreads();
    }
    int bf = *flagp;
#pragma unroll
    for (int tj = 0; tj < 4; ++tj) {
        int n = wn + tj * 16 + ln;
        float bias = ldin(braw, bOff + n, bf);
#pragma unroll
        for (int ti = 0; ti < 2; ++ti)
#pragma unroll
            for (int r = 0; r < 4; ++r) {
                int m = m0 + wm + ti * 16 + q * 4 + r;
                float v = acc[ti][tj][r] + bias;
                float* dst = C + (size_t)m * 128 + n;
                if (resid) v += *dst;
                *dst = v;
                Ct[m - m0][n] = v;
                if (outp) {
                    if (bf) ((u16*)outp)[(size_t)m * 128 + n] = f2bf(v);
                    else ((float*)outp)[(size_t)m * 128 + n] = v;
                }
            }
    }
    if (hnout) {
        __syncthreads();
        float gg0 = ldin(lnG, lnOff + lane, bf);
        float gg1 = ldin(lnG, lnOff + lane + 64, bf);
        float bb0 = ldin(lnB, lnOff + lane, bf);
        float bb1 = ldin(lnB, lnOff + lane + 64, bf);
        for (int rr = 0; rr < 16; ++rr) {
            int row = wave * 16 + rr;
            float x0 = Ct[row][lane], x1 = Ct[row][lane + 64];
            float s = x0 + x1, s2v = x0 * x0 + x1 * x1;
#pragma unroll
            for (int o = 32; o; o >>= 1) {
                s += __shfl_xor(s, o);
                s2v += __shfl_xor(s2v, o);
            }
            float mu = s * (1.0f / 128.0f);
            float var = fmaxf(s2v * (1.0f / 128.0f) - mu * mu, 0.0f);
            float rstd = rsqrtf(var + 1e-5f);
            int m = m0 + row;
            hnout[(size_t)m * 128 + lane]      = f2bf((x0 - mu) * rstd * gg0 + bb0);
            hnout[(size_t)m * 128 + lane + 64] = f2bf((x1 - mu) * rstd * gg1 + bb1);
        }
    }
}

// QKV fused, 64-row tiles: grid (256, 3); outputs f16 bits; Q pre-scaled by 0.25
__global__ __launch_bounds__(256, 2) void qkv_mfma_kernel(
    const u16* __restrict__ A, const u16* __restrict__ qkvT_l,
    const void* bqr, const void* bkr, const void* bvr, long bOff,
    u16* __restrict__ Qo, u16* __restrict__ Ko, u16* __restrict__ Vo,
    const int* flagp) {
    int sel = blockIdx.y;
    const u16* WT = qkvT_l + (size_t)sel * 16384;
    const void* braw = sel == 0 ? bqr : (sel == 1 ? bkr : bvr);
    u16* C = sel == 0 ? Qo : (sel == 1 ? Ko : Vo);
    float scale = sel == 0 ? 0.25f : 1.0f;
    __shared__ __align__(16) u16 As[64][40];
    __shared__ __align__(16) u16 Bs[128][40];
    int tid = threadIdx.x;
    int m0 = blockIdx.x * 64;
    int wave = tid >> 6, lane = tid & 63;
    int wm = (wave >> 1) * 32, wn = (wave & 1) * 64;
    int q = lane >> 4, ln = lane & 15;
    f32x4 zero = {0.f, 0.f, 0.f, 0.f};
    f32x4 acc[2][4];
#pragma unroll
    for (int i = 0; i < 2; ++i)
#pragma unroll
        for (int j = 0; j < 4; ++j) acc[i][j] = zero;
    int sar = tid >> 2, sac = (tid & 3) * 8;
    int sbr = tid >> 1, sbc = (tid & 1) * 16;
    const u16* Ap = A + (size_t)(m0 + sar) * 128 + sac;
    const u16* Bp = WT + (size_t)sbr * 128 + sbc;
#pragma unroll
    for (int k0 = 0; k0 < 128; k0 += 32) {
        uint4 av = *(const uint4*)(Ap + k0);
        uint4 b0 = *(const uint4*)(Bp + k0);
        uint4 b1 = *(const uint4*)(Bp + k0 + 8);
        *(uint4*)&As[sar][sac] = av;
        *(uint4*)&Bs[sbr][sbc] = b0; *(uint4*)&Bs[sbr][sbc + 8] = b1;
        __syncthreads();
        short8 af[2], bfv[4];
#pragma unroll
        for (int t = 0; t < 2; ++t) af[t] = *(const short8*)&As[wm + t * 16 + ln][q * 8];
#pragma unroll
        for (int t = 0; t < 4; ++t) bfv[t] = *(const short8*)&Bs[wn + t * 16 + ln][q * 8];
#pragma unroll
        for (int ti = 0; ti < 2; ++ti)
#pragma unroll
            for (int tj = 0; tj < 4; ++tj)
                acc[ti][tj] = __builtin_amdgcn_mfma_f32_16x16x32_bf16(
                    af[ti], bfv[tj], acc[ti][tj], 0, 0, 0);
        __syncthreads();
    }
    int bf = *flagp;
#pragma unroll
    for (int tj = 0; tj < 4; ++tj) {
        int n = wn + tj * 16 + ln;
        float bias = ldin(braw, bOff + n, bf);
#pragma unroll
        for (int ti = 0; ti < 2; ++ti)
#pragma unroll
            for (int r = 0; r < 4; ++r) {
                int m = m0 + wm + ti * 16 + q * 4 + r;
                C[(size_t)m * 128 + n] = f2h((acc[ti][tj][r] + bias) * scale);
            }
    }
}

// GLU-FF1 (unchanged)
__global__ __launch_bounds__(256, 2) void glu_mfma_kernel(
    const u16* __restrict__ A, const u16* __restrict__ f1T_l,
    const void* __restrict__ braw, long bOff, u16* __restrict__ Vout,
    const int* flagp) {
    __shared__ __align__(16) u16 As[128][40];
    __shared__ __align__(16) u16 Ba[64][40];
    __shared__ __align__(16) u16 Bb[64][40];
    int tid = threadIdx.x;
    int m0 = blockIdx.x * 128, n0 = blockIdx.y * 64;
    int wave = tid >> 6, lane = tid & 63;
    int wm = (wave >> 1) * 64, wn = (wave & 1) * 32;
    int q = lane >> 4, ln = lane & 15;
    f32x4 zero = {0.f, 0.f, 0.f, 0.f};
    f32x4 accA[4][2], accB[4][2];
#pragma unroll
    for (int i = 0; i < 4; ++i)
#pragma unroll
        for (int j = 0; j < 2; ++j) { accA[i][j] = zero; accB[i][j] = zero; }
    int sr = tid >> 1, sc = (tid & 1) * 16;
    const u16* Ap = A + (size_t)(m0 + sr) * 128 + sc;
    const u16* BpA = f1T_l + (size_t)(n0 + sr) * 128 + sc;
    const u16* BpB = f1T_l + (size_t)(512 + n0 + (sr - 64)) * 128 + sc;
#pragma unroll
    for (int k0 = 0; k0 < 128; k0 += 32) {
        uint4 a0 = *(const uint4*)(Ap + k0);
        uint4 a1 = *(const uint4*)(Ap + k0 + 8);
        *(uint4*)&As[sr][sc] = a0; *(uint4*)&As[sr][sc + 8] = a1;
        if (sr < 64) {
            uint4 w0 = *(const uint4*)(BpA + k0);
            uint4 w1 = *(const uint4*)(BpA + k0 + 8);
            *(uint4*)&Ba[sr][sc] = w0; *(uint4*)&Ba[sr][sc + 8] = w1;
        } else {
            uint4 w0 = *(const uint4*)(BpB + k0);
            uint4 w1 = *(const uint4*)(BpB + k0 + 8);
            *(uint4*)&Bb[sr - 64][sc] = w0; *(uint4*)&Bb[sr - 64][sc + 8] = w1;
        }
        __syncthreads();
        short8 af[4], ba[2], bb[2];
#pragma unroll
        for (int t = 0; t < 4; ++t) af[t] = *(const short8*)&As[wm + t * 16 + ln][q * 8];
#pragma unroll
        for (int t = 0; t < 2; ++t) {
            ba[t] = *(const short8*)&Ba[wn + t * 16 + ln][q * 8];
            bb[t] = *(const short8*)&Bb[wn + t * 16 + ln][q * 8];
        }
#pragma unroll
        for (int ti = 0; ti < 4; ++ti)
#pragma unroll
            for (int tj = 0; tj < 2; ++tj) {
                accA[ti][tj] = __builtin_amdgcn_mfma_f32_16x16x32_bf16(
                    af[ti], ba[tj], accA[ti][tj], 0, 0, 0);
                accB[ti][tj] = __builtin_amdgcn_mfma_f32_16x16x32_bf16(
                    af[ti], bb[tj], accB[ti][tj], 0, 0, 0);
            }
        __syncthreads();
    }
    int bf = *flagp;
#pragma unroll
    for (int tj = 0; tj < 2; ++tj) {
        int n = n0 + wn + tj * 16 + ln;
        float biasA = ldin(braw, bOff + n, bf);
        float biasB = ldin(braw, bOff + 512 + n, bf);
#pragma unroll
        for (int ti = 0; ti < 4; ++ti)
#pragma unroll
            for (int r = 0; r < 4; ++r) {
                int m = m0 + wm + ti * 16 + q * 4 + r;
                float ua = accA[ti][tj][r] + biasA;
                float ub = accB[ti][tj][r] + biasB;
                Vout[(size_t)m * 512 + n] = f2bf(ua / (1.0f + __expf(-ub)));
            }
    }
}

// ========== attention v6: 16x16x16 MFMA, zero P round-trip, mask-compressed ==========
// S^T = K Q^T via mfma_f32_16x16x16_f16 (K-dim = HD = 16, all lanes used).
// KEY TRICK: S^T's C-layout (key=quad*4+r, q=ln) IS the A-frag layout
// A[m=ln][k=quad*4+j] for the PV mfma — exp(S^T) feeds PV directly in regs.
// LDS 37.1 KB -> 4 blocks/CU. Bias via ds_bpermute LUT; fixed-shift softmax.
__global__ __launch_bounds__(256, 4) void attn_kernel(
    const u16* __restrict__ Qh, const u16* __restrict__ Kh,
    const u16* __restrict__ Vh, const unsigned char* __restrict__ binsc,
    const u16* __restrict__ kidxg, const int* __restrict__ nktp,
    const unsigned* __restrict__ tmaskp, const float* __restrict__ deL,
    const float* __restrict__ abL, u16* __restrict__ out) {
    // de-swizzle: heads of one (b,qq) share id%8 -> same XCD L2 for binsc
    int id = blockIdx.x;
    int c = id & 7, t5 = id >> 3;
    int nh = t5 & 7;
    int pair = ((t5 >> 3) << 3) | c;
    int b = pair >> 2, qq = pair & 3;

    __shared__ __align__(16) u16 KsF[512 * 20];  // K rows, stride 20 f16 (40B), 20 KB
    __shared__ __align__(16) u16 VT[16 * 520];   // V^T rows 520 f16, 16.6 KB

    int tid = threadIdx.x;
    int nt = __builtin_amdgcn_readfirstlane(nktp[b]);
    int nkp = nt * 32;
    const u16* Kp = Kh + (size_t)(b * Nq) * Hq + nh * HDq;
    const u16* Vp = Vh + (size_t)(b * Nq) * Hq + nh * HDq;
    for (int r = tid; r < nkp; r += 256) {
        int row = kidxg[b * 512 + r];
        uint4 k0v = *(const uint4*)(Kp + (size_t)row * Hq);
        uint4 k1v = *(const uint4*)(Kp + (size_t)row * Hq + 8);
        *(uint2*)&KsF[r * 20]      = make_uint2(k0v.x, k0v.y);
        *(uint2*)&KsF[r * 20 + 4]  = make_uint2(k0v.z, k0v.w);
        *(uint2*)&KsF[r * 20 + 8]  = make_uint2(k1v.x, k1v.y);
        *(uint2*)&KsF[r * 20 + 12] = make_uint2(k1v.z, k1v.w);
        uint4 v0 = *(const uint4*)(Vp + (size_t)row * Hq);
        uint4 v1 = *(const uint4*)(Vp + (size_t)row * Hq + 8);
        u16 vv[16];
        *(uint4*)&vv[0] = v0; *(uint4*)&vv[8] = v1;
#pragma unroll
        for (int d = 0; d < 16; ++d) VT[d * 520 + r] = vv[d];
    }
    __syncthreads();

    int wave = tid >> 6, lane = tid & 63;
    int quad = lane >> 4, ln = lane & 15;
    int q0w = qq * 128 + wave * 32;

    float tblf = (lane < 50) ? deL[lane * NHq + nh] + abL[nh] : 0.0f;
    int tbli = __float_as_int(tblf);
    unsigned tl = tmaskp[b * 16 + nt - 1];

    // Q B-frags for 16x16x16: B[n=q][k=d=quad*4+j] -> uint2 global load
    half4 qf[2];
#pragma unroll
    for (int t = 0; t < 2; ++t) {
        uint2 qv = *(const uint2*)(Qh + (size_t)(b * Nq + q0w + t * 16 + ln) * Hq
                                   + nh * HDq + quad * 4);
        qf[t] = *(half4*)&qv;
    }

    f32x4 zero = {0.f, 0.f, 0.f, 0.f};
    f32x4 acc[2] = {zero, zero};
    float zp[2] = {0.f, 0.f};
    const _Float16* KsH = (const _Float16*)KsF;
    const _Float16* VTH = (const _Float16*)VT;
    const unsigned char* brow0 = binsc + ((size_t)b * 512 + (q0w + ln)) * 512;
    const unsigned char* brow1 = brow0 + (size_t)16 * 512;

    // prefetch kt=0 bias-byte dwords
    unsigned pb00 = *(const unsigned*)(brow0 + quad * 4);
    unsigned pb01 = *(const unsigned*)(brow0 + 16 + quad * 4);
    unsigned pb10 = *(const unsigned*)(brow1 + quad * 4);
    unsigned pb11 = *(const unsigned*)(brow1 + 16 + quad * 4);

    for (int kt = 0; kt < nt; ++kt) {
        int k0 = kt * 32;
        unsigned w = (kt == nt - 1) ? tl : 0u;
        unsigned cb00 = pb00, cb01 = pb01, cb10 = pb10, cb11 = pb11;
        if (kt < nt - 1) {
            pb00 = *(const unsigned*)(brow0 + k0 + 32 + quad * 4);
            pb01 = *(const unsigned*)(brow0 + k0 + 48 + quad * 4);
            pb10 = *(const unsigned*)(brow1 + k0 + 32 + quad * 4);
            pb11 = *(const unsigned*)(brow1 + k0 + 48 + quad * 4);
        }
        // K A-frags: A[m=key-in-tile=ln][k=d=quad*4+j]
        half4 ka0 = *(const half4*)(KsH + (size_t)(k0 + ln) * 20 + quad * 4);
        half4 ka1 = *(const half4*)(KsH + (size_t)(k0 + 16 + ln) * 20 + quad * 4);
        // V B-frags: B[n=d=ln][k=key=quad*4+j]
        half4 vb0 = *(const half4*)(VTH + ln * 520 + k0 + quad * 4);
        half4 vb1 = *(const half4*)(VTH + ln * 520 + k0 + 16 + quad * 4);
#pragma unroll
        for (int t = 0; t < 2; ++t) {
            unsigned bw0 = t == 0 ? cb00 : cb10;
            unsigned bw1 = t == 0 ? cb01 : cb11;
            f32x4 s0 = __builtin_amdgcn_mfma_f32_16x16x16f16(ka0, qf[t], zero, 0, 0, 0);
            f32x4 s1 = __builtin_amdgcn_mfma_f32_16x16x16f16(ka1, qf[t], zero, 0, 0, 0);
            float p[8];
#pragma unroll
            for (int r = 0; r < 4; ++r) {
                float bias = __int_as_float(__builtin_amdgcn_ds_bpermute(
                    (int)((bw0 >> (8 * r)) & 0xFFu), tbli));
                float sc = s0[r] + bias;
                bool m = (w >> (quad * 4 + r)) & 1u;
                p[r] = m ? 0.0f : __expf(sc);
            }
#pragma unroll
            for (int r = 0; r < 4; ++r) {
                float bias = __int_as_float(__builtin_amdgcn_ds_bpermute(
                    (int)((bw1 >> (8 * r)) & 0xFFu), tbli));
                float sc = s1[r] + bias;
                bool m = (w >> (16 + quad * 4 + r)) & 1u;
                p[4 + r] = m ? 0.0f : __expf(sc);
            }
            zp[t] += ((p[0] + p[1]) + (p[2] + p[3])) +
                     ((p[4] + p[5]) + (p[6] + p[7]));
            // exp(S^T) is already in PV A-frag layout: pack & feed directly
            uint2 pw0 = make_uint2(pk2h(p[0], p[1]), pk2h(p[2], p[3]));
            uint2 pw1 = make_uint2(pk2h(p[4], p[5]), pk2h(p[6], p[7]));
            half4 pa0 = *(half4*)&pw0;
            half4 pa1 = *(half4*)&pw1;
            acc[t] = __builtin_amdgcn_mfma_f32_16x16x16f16(pa0, vb0, acc[t], 0, 0, 0);
            acc[t] = __builtin_amdgcn_mfma_f32_16x16x16f16(pa1, vb1, acc[t], 0, 0, 0);
        }
    }
#pragma unroll
    for (int t = 0; t < 2; ++t) {
        zp[t] += __shfl_xor(zp[t], 16);
        zp[t] += __shfl_xor(zp[t], 32);
    }
    // acc C-layout: row = q = quad*4+r, col = d = ln
#pragma unroll
    for (int t = 0; t < 2; ++t) {
#pragma unroll
        for (int r = 0; r < 4; ++r) {
            float zz = __shfl(zp[t], quad * 4 + r);
            float val = acc[t][r] / fmaxf(zz, 1e-35f);
            int qrow = q0w + t * 16 + quad * 4 + r;
            out[(size_t)(b * Nq + qrow) * Hq + nh * HDq + ln] = f2bf(val);
        }
    }
}

extern "C" void kernel_launch(void* const* d_in, const int* in_sizes, int n_in,
                              void* d_out, int out_size, void* d_ws, size_t ws_size,
                              hipStream_t stream) {
    const void* x  = d_in[0];
    const void* dist = d_in[1];
    const void* mask = d_in[2];
    const void* Wq = d_in[3];  const void* bq = d_in[4];
    const void* Wk = d_in[5];  const void* bk = d_in[6];
    const void* Wv = d_in[7];  const void* bv = d_in[8];
    const void* Wo = d_in[9];  const void* bo = d_in[10];
    const void* de = d_in[11]; const void* ab = d_in[12];
    const void* g1 = d_in[13]; const void* b1 = d_in[14];
    const void* g2 = d_in[15]; const void* b2 = d_in[16];
    const void* Wf1 = d_in[17]; const void* bf1 = d_in[18];
    const void* Wf2 = d_in[19]; const void* bf2 = d_in[20];

    char* ws = (char*)d_ws;
    const size_t OFF_DE   = 64;
    const size_t OFF_AB   = 5120;
    const size_t OFF_BINS = 8192;                    // binsc 8,388,608
    const size_t OFF_MSK  = OFF_BINS + 8388608;      // mbits 2 KB (4096 res)
    const size_t OFF_KIDX = OFF_MSK + 4096;          // 32768
    const size_t OFF_NKT  = OFF_KIDX + 32768;        // 256
    const size_t OFF_TM   = OFF_NKT + 256;           // 2048
    const size_t OFF_H    = OFF_TM + 4096;           // f32 8,388,608
    const size_t OFF_QKV  = OFF_H + 8388608;         // Qh,Kh,Vh f16 | vglu u16 16MB
    const size_t OFF_HN   = OFF_QKV + 25165824;      // u16 4,194,304
    const size_t OFF_ATT  = OFF_HN + 4194304;        // u16 4,194,304
    const size_t OFF_WT   = OFF_ATT + 4194304;       // u16 1,572,864
    const size_t NEEDED   = OFF_WT + 1572864;
    if (ws_size < NEEDED) return;

    int* flag = (int*)ws;
    float* deF = (float*)(ws + OFF_DE);
    float* abF = (float*)(ws + OFF_AB);
    unsigned char* binsc = (unsigned char*)(ws + OFF_BINS);
    unsigned* mbits = (unsigned*)(ws + OFF_MSK);
    u16* kidxg = (u16*)(ws + OFF_KIDX);
    int* nkt = (int*)(ws + OFF_NKT);
    unsigned* tmask = (unsigned*)(ws + OFF_TM);
    float* h = (float*)(ws + OFF_H);
    u16* Qh = (u16*)(ws + OFF_QKV);
    u16* Kh = Qh + 2097152;
    u16* Vh = Qh + 2 * 2097152;
    u16* vglu = (u16*)(ws + OFF_QKV);
    u16* hn = (u16*)(ws + OFF_HN);
    u16* att = (u16*)(ws + OFF_ATT);
    u16* qkvT = (u16*)(ws + OFF_WT);
    u16* oT  = qkvT + 147456;
    u16* f1T = oT + 49152;
    u16* f2T = f1T + 393216;

    prep_kernel<<<1, 256, 0, stream>>>(x, de, ab, mask, flag, deF, abF, mbits, Bq * Nq);
    kprep_kernel<<<32, 64, 0, stream>>>(mbits, kidxg, nkt, tmask);
    dim3 gbc(64, 32);
    binsc_kernel<<<gbc, 256, 0, stream>>>(dist, kidxg, nkt, binsc, flag);
    init_ln_kernel<<<4096, 256, 0, stream>>>(x, h, hn, g1, b1, flag);
    wtrans_kernel<<<768, 256, 0, stream>>>(Wq, Wk, Wv, Wo, Wf1, Wf2,
                                           qkvT, oT, f1T, f2T, flag);

    dim3 gqkv(256, 3);
    dim3 gglu(128, 8);
    for (int l = 0; l < 3; ++l) {
        qkv_mfma_kernel<<<gqkv, 256, 0, stream>>>(hn, qkvT + (size_t)l * 49152,
                                                  bq, bk, bv, (long)l * Hq,
                                                  Qh, Kh, Vh, flag);
        attn_kernel<<<1024, 256, 0, stream>>>(Qh, Kh, Vh, binsc, kidxg, nkt, tmask,
                                              deF + (long)l * 400, abF + (long)l * 8, att);
        // o-proj + residual + fused LN2 -> h, hn
        mfma_gemm64_kernel<<<256, 256, 0, stream>>>(att, oT + (size_t)l * 16384,
                                                    bo, (long)l * Hq, h, 128, 1, flag,
                                                    g2, b2, (long)l * Hq, hn, nullptr);
        glu_mfma_kernel<<<gglu, 256, 0, stream>>>(hn, f1T + (size_t)l * 131072,
                                                  bf1, (long)l * 1024, vglu, flag);
        if (l < 2) {
            mfma_gemm64_kernel<<<256, 256, 0, stream>>>(vglu, f2T + (size_t)l * 65536,
                                                        bf2, (long)l * Hq, h, 512, 1, flag,
                                                        g1, b1, (long)(l + 1) * Hq, hn,
                                                        nullptr);
        } else {
            mfma_gemm64_kernel<<<256, 256, 0, stream>>>(vglu, f2T + (size_t)l * 65536,
                                                        bf2, (long)l * Hq, h, 512, 1, flag,
                                                        nullptr, nullptr, 0, nullptr,
                                                        d_out);
        }
    }
}